// Round 15
// baseline (137.733 us; speedup 1.0000x reference)
//
#include <hip/hip_runtime.h>

typedef _Float16 f16x8 __attribute__((ext_vector_type(8)));
typedef _Float16 f16x4 __attribute__((ext_vector_type(4)));
typedef _Float16 f16x2 __attribute__((ext_vector_type(2)));
typedef float    f32x4 __attribute__((ext_vector_type(4)));
typedef unsigned u32x4 __attribute__((ext_vector_type(4)));
typedef unsigned long long u64;

constexpr int Bc = 4, Hc = 16, Sc = 2048, Dc = 64;
constexpr int KVBLK = 64;
constexpr int NKV = Sc / KVBLK;   // 32
constexpr int QB  = 256;          // q rows per block (4 waves x 64: 4 fragments/wave)
constexpr int NQT = Sc / QB;      // 8
constexpr int NQ  = 32;           // mask row-block granularity (64 rows)

__device__ __forceinline__ float fast_exp2(float x) {
#if __has_builtin(__builtin_amdgcn_exp2f)
  return __builtin_amdgcn_exp2f(x);
#else
  return exp2f(x);
#endif
}

__device__ __forceinline__ void gload16(const void* g, void* l) {
  __builtin_amdgcn_global_load_lds(
      (const __attribute__((address_space(1))) void*)g,
      (__attribute__((address_space(3))) void*)l, 16, 0, 0);
}

__device__ __forceinline__ f32x4 mfma16(f16x8 a, f16x8 b, f32x4 c) {
  return __builtin_amdgcn_mfma_f32_16x16x32_f16(a, b, c, 0, 0, 0);
}

__device__ __forceinline__ unsigned pkrtz(float x, float y) {
  return __builtin_bit_cast(unsigned, __builtin_amdgcn_cvt_pkrtz(x, y));
}

__device__ __forceinline__ float dot2acc(unsigned pk, float acc) {
#if __has_builtin(__builtin_amdgcn_fdot2)
  const f16x2 one2 = {(_Float16)1.f, (_Float16)1.f};
  return __builtin_amdgcn_fdot2(__builtin_bit_cast(f16x2, pk), one2, acc, false);
#else
  const f16x2 v = __builtin_bit_cast(f16x2, pk);
  return acc + (float)v[0] + (float)v[1];
#endif
}

// ---- Prepass A: K fp32 [bh][s][d] -> fp16 XOR-swizzled tiles ----
__global__ __launch_bounds__(256)
void cvt_k_sw(const float* __restrict__ K, _Float16* __restrict__ Ko) {
  const int tile = blockIdx.x;              // bh*32 + kvt
  const int t = threadIdx.x;
  const float* src = K + (size_t)tile * 4096;
  _Float16* dst = Ko + (size_t)tile * 4096;
  #pragma unroll
  for (int cc = 0; cc < 2; ++cc) {
    const int c = t + cc * 256;
    const int r = c >> 3, s = c & 7;
    const int ss = s ^ (r & 7);
    const float* p = src + r * 64 + ss * 8;
    const float4 a = *(const float4*)p;
    const float4 b2 = *(const float4*)(p + 4);
    f16x8 h = {(_Float16)a.x, (_Float16)a.y, (_Float16)a.z, (_Float16)a.w,
               (_Float16)b2.x, (_Float16)b2.y, (_Float16)b2.z, (_Float16)b2.w};
    *(f16x8*)(dst + (size_t)c * 8) = h;
  }
}

// ---- Prepass B: V -> fp16, transposed [d][key], keys PERMUTED by pi, XOR-swizzled ----
// pi(s): s = ks*32 + 8*lg + e  ->  key = 32*ks + 16*(e>>2) + 4*lg + (e&3)
__global__ __launch_bounds__(256)
void cvt_v_sw(const float* __restrict__ V, _Float16* __restrict__ Vo) {
  __shared__ float tile[64][65];            // [key][d]
  const int tb = blockIdx.x;                // bh*32 + kvt
  const int t = threadIdx.x;
  const float* src = V + (size_t)tb * 4096;
  {
    const int r = t >> 2, c0 = (t & 3) * 16;
    #pragma unroll
    for (int j = 0; j < 16; j += 4)
      *(float4*)&tile[r][c0 + j] = *(const float4*)(src + r * 64 + c0 + j);
  }
  __syncthreads();
  _Float16* dst = Vo + (size_t)tb * 4096;
  #pragma unroll
  for (int cc = 0; cc < 2; ++cc) {
    const int c = t + cc * 256;
    const int d = c >> 3, ss = c & 7;
    const int m = ss ^ (d & 7);             // logical chunk = ks*4+lg
    const int ks = m >> 2, lg = m & 3;
    f16x8 h;
    #pragma unroll
    for (int e = 0; e < 8; ++e) {
      const int key = 32 * ks + 16 * (e >> 2) + 4 * lg + (e & 3);
      h[e] = (_Float16)tile[key][d];
    }
    *(f16x8*)(dst + (size_t)c * 8) = h;
  }
}

// ---- Prepass C: mask int32 -> bits[b][row>>6][kv][row&63] u64 ----
__global__ __launch_bounds__(256)
void pack_mask(const int* __restrict__ M, u64* __restrict__ MB) {
  const int gid  = blockIdx.x * 256 + threadIdx.x;
  const int wv   = gid >> 6, lane = gid & 63;
  const int kv   = wv & (NKV - 1);
  const int row  = (wv >> 5) & (Sc - 1);
  const int b    = wv >> 16;
  const int m    = M[((size_t)b * Sc + row) * Sc + (size_t)kv * 64 + lane];
  const u64 bits = __ballot(m != 0);
  if (lane == 0)
    MB[(((size_t)b * NQ + (row >> 6)) * NKV + kv) * 64 + (row & 63)] = bits;
}

// ---- Main: 4 waves x 64q (4 fragments), halved LDS traffic, counted-vmcnt pipeline ----
// LDS (bytes): buf*16384 + {K:0 | V:8192} + nt*2048 + lc*128 + slot*16
// slot(ks) = (ks*4 + lg) ^ (lc&7)   [16x16 pattern: 0 bank conflicts, rounds 6-13]
__global__ __launch_bounds__(256, 2)
void attn_fwd13(const float* __restrict__ Q, const _Float16* __restrict__ Ksw,
                const _Float16* __restrict__ Vsw, const u64* __restrict__ MB,
                float* __restrict__ O)
{
  // XCD-chunked swizzle: 512 blocks = 8 XCDs x 64
  const int bid = (blockIdx.x & 7) * 64 + (blockIdx.x >> 3);
  const int qt  = bid & (NQT - 1);
  const int bh  = bid >> 3;
  const int b   = bh >> 4;
  const int q0  = qt * QB;

  const int tid = threadIdx.x;
  const int w   = tid >> 6;    // 0..3 (wave owns q rows [64w, 64w+64))
  const int l   = tid & 63;
  const int lg  = l >> 4;      // 0..3
  const int lc  = l & 15;      // 0..15

  __shared__ _Float16 SB[16384];   // 32 KB: 2 bufs x (K 8KB | V 8KB)
  const char* sb = (const char*)SB;

  const int a0 = lc * 128 + (((0 + lg) ^ (lc & 7)) << 4);
  const int a1 = lc * 128 + (((4 + lg) ^ (lc & 7)) << 4);

  // Q fragments (B operand), 4 per wave: col=q=16*qa+lc, k=ks*32+8*lg+e
  f16x8 qf[4][2];
  {
    const float qs = 0.125f * 1.4426950408889634f;
    #pragma unroll
    for (int qa = 0; qa < 4; ++qa) {
      const float* qr = Q + ((size_t)bh * Sc + q0 + w * 64 + qa * 16 + lc) * Dc + 8 * lg;
      #pragma unroll
      for (int ks = 0; ks < 2; ++ks) {
        f16x8 t;
        #pragma unroll
        for (int e = 0; e < 8; ++e) t[e] = (_Float16)(qr[ks * 32 + e] * qs);
        qf[qa][ks] = t;
      }
    }
  }

  f32x4 o_acc[4][4];
  #pragma unroll
  for (int qa = 0; qa < 4; ++qa)
    #pragma unroll
    for (int nt = 0; nt < 4; ++nt) o_acc[qa][nt] = (f32x4){0.f, 0.f, 0.f, 0.f};
  float l_acc[4] = {0.f, 0.f, 0.f, 0.f};
  const float NEGL = -1.4426950e9f;   // exp2 -> exact 0 for masked keys

  const char* KswT = (const char*)(Ksw + (size_t)bh * Sc * Dc);
  const char* VswT = (const char*)(Vsw + (size_t)bh * Sc * Dc);
  // rows [q0+w*64, q0+w*64+64) live in ONE 64-row mask block: (q0>>6)+w
  const u64* Mb = MB + ((size_t)(b * NQ + (q0 >> 6) + w) * NKV) * 64 + lc;

  // stage: wave w copies 4 KB of the 16 KB tile (K: waves 0-1, V: waves 2-3)
  auto stage = [&](int kvt, int buf) {
    const char* g = (w < 2) ? KswT + (size_t)kvt * 8192 + w * 4096
                            : VswT + (size_t)kvt * 8192 + (w - 2) * 4096;
    char* lb = (char*)SB + buf * 16384 + ((w < 2) ? w * 4096 : 8192 + (w - 2) * 4096);
    #pragma unroll
    for (int j = 0; j < 4; ++j)
      gload16(g + j * 1024 + l * 16, lb + j * 1024);
  };

  auto body = [&](int buf, u64 m0, u64 m1, u64 m2, u64 m3) {
    const int base = buf * 16384;
    // --- QK cluster: 32 MFMA, K fragments read once per nt ---
    f32x4 p[4][4];
    __builtin_amdgcn_s_setprio(1);
    #pragma unroll
    for (int nt = 0; nt < 4; ++nt) {
      const f16x8 k0 = *(const f16x8*)(sb + base + nt * 2048 + a0);
      const f16x8 k1 = *(const f16x8*)(sb + base + nt * 2048 + a1);
      #pragma unroll
      for (int qa = 0; qa < 4; ++qa) {
        f32x4 acc = (f32x4){0.f, 0.f, 0.f, 0.f};
        acc = mfma16(k0, qf[qa][0], acc);
        acc = mfma16(k1, qf[qa][1], acc);
        p[qa][nt] = acc;
      }
    }
    __builtin_amdgcn_s_setprio(0);
    // --- softmax cluster: constant-max, pe = exp2(mask ? s : NEGL) ---
    f16x8 pa0[4], pa1[4];
    #pragma unroll
    for (int qa = 0; qa < 4; ++qa) {
      const u64 mbits = (qa == 0) ? m0 : (qa == 1) ? m1 : (qa == 2) ? m2 : m3;
      #pragma unroll
      for (int nt = 0; nt < 4; ++nt) {
        const unsigned b4 = ((unsigned)(mbits >> (nt * 16 + 4 * lg))) & 0xFu;
        #pragma unroll
        for (int r = 0; r < 4; ++r)
          p[qa][nt][r] = fast_exp2(((b4 >> r) & 1u) ? p[qa][nt][r] : NEGL);
      }
      u32x4 u0, u1;
      #pragma unroll
      for (int i = 0; i < 4; ++i) {
        u0[i] = pkrtz(p[qa][i >> 1][(i & 1) * 2], p[qa][i >> 1][(i & 1) * 2 + 1]);
        u1[i] = pkrtz(p[qa][2 + (i >> 1)][(i & 1) * 2], p[qa][2 + (i >> 1)][(i & 1) * 2 + 1]);
      }
      float la = l_acc[qa];
      #pragma unroll
      for (int i = 0; i < 4; ++i) { la = dot2acc(u0[i], la); la = dot2acc(u1[i], la); }
      l_acc[qa] = la;
      pa0[qa] = __builtin_bit_cast(f16x8, u0);
      pa1[qa] = __builtin_bit_cast(f16x8, u1);
    }
    // --- PV cluster: 32 MFMA, V fragments read once per nt ---
    __builtin_amdgcn_s_setprio(1);
    #pragma unroll
    for (int nt = 0; nt < 4; ++nt) {
      const f16x8 v0 = *(const f16x8*)(sb + base + 8192 + nt * 2048 + a0);
      const f16x8 v1 = *(const f16x8*)(sb + base + 8192 + nt * 2048 + a1);
      #pragma unroll
      for (int qa = 0; qa < 4; ++qa) {
        o_acc[qa][nt] = mfma16(pa0[qa], v0, o_acc[qa][nt]);
        o_acc[qa][nt] = mfma16(pa1[qa], v1, o_acc[qa][nt]);
      }
    }
    __builtin_amdgcn_s_setprio(0);
  };

  // ---- counted-vmcnt 2-buffer pipeline (per half-iter vmem = 4 gload + 4 mask = 8) ----
  u64 mA0 = Mb[0], mA1 = Mb[16], mA2 = Mb[32], mA3 = Mb[48];
  stage(0, 0);
  asm volatile("s_waitcnt vmcnt(0)" ::: "memory");
  __builtin_amdgcn_sched_barrier(0);
  __builtin_amdgcn_s_barrier();

  u64 mB0, mB1, mB2, mB3;
  for (int t = 0; t < NKV; t += 2) {
    // --- prefetch tile t+1 into B1, then run body(t) on B0 ---
    stage(t + 1, 1);
    {
      const size_t mo = (size_t)(t + 1) * 64;
      mB0 = Mb[mo]; mB1 = Mb[mo + 16]; mB2 = Mb[mo + 32]; mB3 = Mb[mo + 48];
    }
    asm volatile("s_waitcnt vmcnt(8)" ::: "memory");  // only stage(t+1)+masks in flight
    __builtin_amdgcn_sched_barrier(0);
    __builtin_amdgcn_s_barrier();                      // B0 ready for all waves
    body(0, mA0, mA1, mA2, mA3);
    __builtin_amdgcn_s_barrier();                      // B0 readers done (WAR)

    // --- prefetch tile t+2 into B0, then run body(t+1) on B1 ---
    if (t + 2 < NKV) {
      stage(t + 2, 0);
      const size_t mo = (size_t)(t + 2) * 64;
      mA0 = Mb[mo]; mA1 = Mb[mo + 16]; mA2 = Mb[mo + 32]; mA3 = Mb[mo + 48];
      asm volatile("s_waitcnt vmcnt(8)" ::: "memory");
    } else {
      asm volatile("s_waitcnt vmcnt(0)" ::: "memory");
    }
    __builtin_amdgcn_sched_barrier(0);
    __builtin_amdgcn_s_barrier();                      // B1 ready
    body(1, mB0, mB1, mB2, mB3);
    __builtin_amdgcn_s_barrier();                      // B1 readers done
  }

  // ---- epilogue: reduce l (additive), O /= l ----
  #pragma unroll
  for (int qa = 0; qa < 4; ++qa) {
    float la = l_acc[qa];
    la += __shfl_xor(la, 16, 64);
    la += __shfl_xor(la, 32, 64);
    #pragma unroll
    for (int r = 0; r < 4; ++r) {
      const float li = 1.0f / __shfl(la, 4 * lg + r, 64);
      float* orow = O + ((size_t)bh * Sc + q0 + w * 64 + qa * 16 + 4 * lg + r) * Dc + lc;
      #pragma unroll
      for (int nt = 0; nt < 4; ++nt)
        orow[nt * 16] = o_acc[qa][nt][r] * li;
    }
  }
}

// ---------------- Fallback (round-1 kernel, used if ws too small) ----------------
constexpr int LDSW = KVBLK + 8;

__global__ __launch_bounds__(256)
void attn_fwd_v1(const float* __restrict__ Q, const float* __restrict__ K,
                 const float* __restrict__ V, const int* __restrict__ M,
                 float* __restrict__ O)
{
  const int bid   = blockIdx.x;
  const int qtile = bid & 31;
  const int bh    = bid >> 5;
  const int b     = bh >> 4;

  const float* Qp = Q + ((size_t)bh * Sc + (size_t)qtile * 64) * Dc;
  const float* Kp = K + (size_t)bh * Sc * Dc;
  const float* Vp = V + (size_t)bh * Sc * Dc;
  const int*   Mp = M + (size_t)b * Sc * Sc + (size_t)qtile * 64 * Sc;
  float*       Op = O + ((size_t)bh * Sc + (size_t)qtile * 64) * Dc;

  __shared__ _Float16 Klds [KVBLK][LDSW];
  __shared__ _Float16 Vtlds[Dc]   [LDSW];
  __shared__ _Float16 Pl   [64]   [LDSW];

  const int tid = threadIdx.x;
  const int w   = tid >> 6;
  const int l   = tid & 63;
  const int lg  = l >> 4;
  const int lc  = l & 15;

  f16x8 qf[2];
  {
    const float qs = 0.125f * 1.4426950408889634f;
    const float* qrow = Qp + (size_t)(w * 16 + lc) * Dc + 8 * lg;
    #pragma unroll
    for (int ks = 0; ks < 2; ++ks) {
      f16x8 t;
      #pragma unroll
      for (int e = 0; e < 8; ++e) t[e] = (_Float16)(qrow[ks * 32 + e] * qs);
      qf[ks] = t;
    }
  }

  f32x4 o_acc[4];
  #pragma unroll
  for (int nt = 0; nt < 4; ++nt) o_acc[nt] = (f32x4){0.f, 0.f, 0.f, 0.f};
  float m_r[4], l_r[4];
  #pragma unroll
  for (int r = 0; r < 4; ++r) { m_r[r] = -3.0e38f; l_r[r] = 0.f; }
  const float NEGL = -1.4426950e9f;

  for (int kv = 0; kv < NKV; ++kv) {
    const float* Kt = Kp + (size_t)kv * KVBLK * Dc;
    const float* Vt = Vp + (size_t)kv * KVBLK * Dc;
    __syncthreads();
    {
      const int r = tid >> 2, c0 = (tid & 3) * 16;
      const float* src = Kt + (size_t)r * Dc + c0;
      f16x8 h0, h1;
      #pragma unroll
      for (int e = 0; e < 8; ++e) h0[e] = (_Float16)src[e];
      #pragma unroll
      for (int e = 0; e < 8; ++e) h1[e] = (_Float16)src[8 + e];
      *(f16x8*)&Klds[r][c0]     = h0;
      *(f16x8*)&Klds[r][c0 + 8] = h1;
    }
    {
      const int r0 = (tid >> 4) * 4, c0 = (tid & 15) * 4;
      float a_[4][4];
      #pragma unroll
      for (int i = 0; i < 4; ++i) {
        const float4 v4 = *(const float4*)(Vt + (size_t)(r0 + i) * Dc + c0);
        a_[i][0] = v4.x; a_[i][1] = v4.y; a_[i][2] = v4.z; a_[i][3] = v4.w;
      }
      #pragma unroll
      for (int j = 0; j < 4; ++j) {
        f16x4 t = {(_Float16)a_[0][j], (_Float16)a_[1][j],
                   (_Float16)a_[2][j], (_Float16)a_[3][j]};
        *(f16x4*)&Vtlds[c0 + j][r0] = t;
      }
    }
    __syncthreads();

    f32x4 s_acc[4];
    #pragma unroll
    for (int nt = 0; nt < 4; ++nt) {
      f32x4 acc = (f32x4){0.f, 0.f, 0.f, 0.f};
      #pragma unroll
      for (int ks = 0; ks < 2; ++ks) {
        f16x8 kf = *(const f16x8*)&Klds[nt * 16 + lc][ks * 32 + 8 * lg];
        acc = __builtin_amdgcn_mfma_f32_16x16x32_f16(qf[ks], kf, acc, 0, 0, 0);
      }
      s_acc[nt] = acc;
    }

    const int* mbase = Mp + (size_t)kv * KVBLK + lc;
    #pragma unroll
    for (int r = 0; r < 4; ++r) {
      const int qrow = w * 16 + 4 * lg + r;
      const int* mr = mbase + (size_t)qrow * Sc;
      float s0 = (mr[0]  != 0) ? s_acc[0][r] : NEGL;
      float s1 = (mr[16] != 0) ? s_acc[1][r] : NEGL;
      float s2 = (mr[32] != 0) ? s_acc[2][r] : NEGL;
      float s3 = (mr[48] != 0) ? s_acc[3][r] : NEGL;
      float mx = fmaxf(fmaxf(s0, s1), fmaxf(s2, s3));
      #pragma unroll
      for (int off = 1; off < 16; off <<= 1)
        mx = fmaxf(mx, __shfl_xor(mx, off, 64));
      const float mn   = fmaxf(m_r[r], mx);
      const float corr = fast_exp2(m_r[r] - mn);
      m_r[r] = mn;
      float p0 = fast_exp2(s0 - mn);
      float p1 = fast_exp2(s1 - mn);
      float p2 = fast_exp2(s2 - mn);
      float p3 = fast_exp2(s3 - mn);
      float rs = (p0 + p1) + (p2 + p3);
      #pragma unroll
      for (int off = 1; off < 16; off <<= 1)
        rs += __shfl_xor(rs, off, 64);
      l_r[r] = l_r[r] * corr + rs;
      #pragma unroll
      for (int nt = 0; nt < 4; ++nt) o_acc[nt][r] *= corr;
      Pl[qrow][lc]      = (_Float16)p0;
      Pl[qrow][16 + lc] = (_Float16)p1;
      Pl[qrow][32 + lc] = (_Float16)p2;
      Pl[qrow][48 + lc] = (_Float16)p3;
    }

    #pragma unroll
    for (int nt = 0; nt < 4; ++nt) {
      #pragma unroll
      for (int ks = 0; ks < 2; ++ks) {
        f16x8 pf = *(const f16x8*)&Pl[w * 16 + lc][ks * 32 + 8 * lg];
        f16x8 vf = *(const f16x8*)&Vtlds[nt * 16 + lc][ks * 32 + 8 * lg];
        o_acc[nt] = __builtin_amdgcn_mfma_f32_16x16x32_f16(pf, vf, o_acc[nt], 0, 0, 0);
      }
    }
  }

  #pragma unroll
  for (int r = 0; r < 4; ++r) {
    const float inv = 1.0f / l_r[r];
    float* orow = Op + (size_t)(w * 16 + 4 * lg + r) * Dc;
    #pragma unroll
    for (int nt = 0; nt < 4; ++nt)
      orow[nt * 16 + lc] = o_acc[nt][r] * inv;
  }
}

extern "C" void kernel_launch(void* const* d_in, const int* in_sizes, int n_in,
                              void* d_out, int out_size, void* d_ws, size_t ws_size,
                              hipStream_t stream) {
  (void)in_sizes; (void)n_in; (void)out_size;
  const float* Q = (const float*)d_in[0];
  const float* K = (const float*)d_in[1];
  const float* V = (const float*)d_in[2];
  const int*   M = (const int*)d_in[3];
  float*       O = (float*)d_out;

  const size_t nKV      = (size_t)Bc * Hc * Sc * Dc;        // 8,388,608
  const size_t bytesK16 = nKV * 2;                           // 16 MiB
  const size_t bytesMB  = (size_t)Bc * NQ * NKV * 64 * 8;    // 2 MiB
  const size_t need     = 2 * bytesK16 + bytesMB;

  if (ws_size >= need) {
    _Float16* K16  = (_Float16*)d_ws;
    _Float16* Vt16 = (_Float16*)((char*)d_ws + bytesK16);
    u64*      MBp  = (u64*)((char*)d_ws + 2 * bytesK16);
    hipLaunchKernelGGL(cvt_k_sw,   dim3(2048),  dim3(256), 0, stream, K, K16);
    hipLaunchKernelGGL(cvt_v_sw,   dim3(2048),  dim3(256), 0, stream, V, Vt16);
    hipLaunchKernelGGL(pack_mask,  dim3(65536), dim3(256), 0, stream, M, MBp);
    hipLaunchKernelGGL(attn_fwd13, dim3(512),   dim3(256), 0, stream, Q, K16, Vt16, MBp, O);
  } else {
    hipLaunchKernelGGL(attn_fwd_v1, dim3(2048), dim3(256), 0, stream, Q, K, V, M, O);
  }
}

// Round 16
// 130.157 us; speedup vs baseline: 1.0582x; 1.0582x over previous
//
#include <hip/hip_runtime.h>

typedef _Float16 f16x8 __attribute__((ext_vector_type(8)));
typedef _Float16 f16x4 __attribute__((ext_vector_type(4)));
typedef _Float16 f16x2 __attribute__((ext_vector_type(2)));
typedef float    f32x4 __attribute__((ext_vector_type(4)));
typedef unsigned u32x4 __attribute__((ext_vector_type(4)));
typedef unsigned long long u64;

constexpr int Bc = 4, Hc = 16, Sc = 2048, Dc = 64;
constexpr int KVBLK = 64;
constexpr int NKV = Sc / KVBLK;   // 32
constexpr int QB  = 256;          // q rows per block (8 waves x 32: 2 fragments/wave)
constexpr int NQT = Sc / QB;      // 8
constexpr int NQ  = 32;           // mask row-block granularity (64 rows)

__device__ __forceinline__ float fast_exp2(float x) {
#if __has_builtin(__builtin_amdgcn_exp2f)
  return __builtin_amdgcn_exp2f(x);
#else
  return exp2f(x);
#endif
}

__device__ __forceinline__ void gload16(const void* g, void* l) {
  __builtin_amdgcn_global_load_lds(
      (const __attribute__((address_space(1))) void*)g,
      (__attribute__((address_space(3))) void*)l, 16, 0, 0);
}

__device__ __forceinline__ f32x4 mfma16(f16x8 a, f16x8 b, f32x4 c) {
  return __builtin_amdgcn_mfma_f32_16x16x32_f16(a, b, c, 0, 0, 0);
}

__device__ __forceinline__ unsigned pkrtz(float x, float y) {
  return __builtin_bit_cast(unsigned, __builtin_amdgcn_cvt_pkrtz(x, y));
}

__device__ __forceinline__ float dot2acc(unsigned pk, float acc) {
#if __has_builtin(__builtin_amdgcn_fdot2)
  const f16x2 one2 = {(_Float16)1.f, (_Float16)1.f};
  return __builtin_amdgcn_fdot2(__builtin_bit_cast(f16x2, pk), one2, acc, false);
#else
  const f16x2 v = __builtin_bit_cast(f16x2, pk);
  return acc + (float)v[0] + (float)v[1];
#endif
}

// ---- Prepass A: K fp32 [bh][s][d] -> fp16 XOR-swizzled tiles ----
__global__ __launch_bounds__(256)
void cvt_k_sw(const float* __restrict__ K, _Float16* __restrict__ Ko) {
  const int tile = blockIdx.x;              // bh*32 + kvt
  const int t = threadIdx.x;
  const float* src = K + (size_t)tile * 4096;
  _Float16* dst = Ko + (size_t)tile * 4096;
  #pragma unroll
  for (int cc = 0; cc < 2; ++cc) {
    const int c = t + cc * 256;
    const int r = c >> 3, s = c & 7;
    const int ss = s ^ (r & 7);
    const float* p = src + r * 64 + ss * 8;
    const float4 a = *(const float4*)p;
    const float4 b2 = *(const float4*)(p + 4);
    f16x8 h = {(_Float16)a.x, (_Float16)a.y, (_Float16)a.z, (_Float16)a.w,
               (_Float16)b2.x, (_Float16)b2.y, (_Float16)b2.z, (_Float16)b2.w};
    *(f16x8*)(dst + (size_t)c * 8) = h;
  }
}

// ---- Prepass B: V -> fp16, transposed [d][key], keys PERMUTED by pi, XOR-swizzled ----
// pi(s): s = ks*32 + 8*lg + e  ->  key = 32*ks + 16*(e>>2) + 4*lg + (e&3)
__global__ __launch_bounds__(256)
void cvt_v_sw(const float* __restrict__ V, _Float16* __restrict__ Vo) {
  __shared__ float tile[64][65];            // [key][d]
  const int tb = blockIdx.x;                // bh*32 + kvt
  const int t = threadIdx.x;
  const float* src = V + (size_t)tb * 4096;
  {
    const int r = t >> 2, c0 = (t & 3) * 16;
    #pragma unroll
    for (int j = 0; j < 16; j += 4)
      *(float4*)&tile[r][c0 + j] = *(const float4*)(src + r * 64 + c0 + j);
  }
  __syncthreads();
  _Float16* dst = Vo + (size_t)tb * 4096;
  #pragma unroll
  for (int cc = 0; cc < 2; ++cc) {
    const int c = t + cc * 256;
    const int d = c >> 3, ss = c & 7;
    const int m = ss ^ (d & 7);             // logical chunk = ks*4+lg
    const int ks = m >> 2, lg = m & 3;
    f16x8 h;
    #pragma unroll
    for (int e = 0; e < 8; ++e) {
      const int key = 32 * ks + 16 * (e >> 2) + 4 * lg + (e & 3);
      h[e] = (_Float16)tile[key][d];
    }
    *(f16x8*)(dst + (size_t)c * 8) = h;
  }
}

// ---- Prepass C: mask int32 -> bits[b][row>>6][kv][row&63] u64 ----
__global__ __launch_bounds__(256)
void pack_mask(const int* __restrict__ M, u64* __restrict__ MB) {
  const int gid  = blockIdx.x * 256 + threadIdx.x;
  const int wv   = gid >> 6, lane = gid & 63;
  const int kv   = wv & (NKV - 1);
  const int row  = (wv >> 5) & (Sc - 1);
  const int b    = wv >> 16;
  const int m    = M[((size_t)b * Sc + row) * Sc + (size_t)kv * 64 + lane];
  const u64 bits = __ballot(m != 0);
  if (lane == 0)
    MB[(((size_t)b * NQ + (row >> 6)) * NKV + kv) * 64 + (row & 63)] = bits;
}

// ---- Main: QB=256, 8 waves x 32q (2 frags), counted-vmcnt pipeline, raw s_barrier ----
// LDS (bytes): buf*16384 + {K:0 | V:8192} + nt*2048 + lc*128 + slot*16
// slot(ks) = (ks*4 + lg) ^ (lc&7)
__global__ __launch_bounds__(512, 4)
void attn_fwd11(const float* __restrict__ Q, const _Float16* __restrict__ Ksw,
                const _Float16* __restrict__ Vsw, const u64* __restrict__ MB,
                float* __restrict__ O)
{
  // XCD-chunked swizzle: 512 blocks = 8 XCDs x 64
  const int bid = (blockIdx.x & 7) * 64 + (blockIdx.x >> 3);
  const int qt  = bid & (NQT - 1);
  const int bh  = bid >> 3;
  const int b   = bh >> 4;
  const int q0  = qt * QB;

  const int tid = threadIdx.x;
  const int w   = tid >> 6;    // 0..7 (wave owns q rows [32w, 32w+32))
  const int l   = tid & 63;
  const int lg  = l >> 4;      // 0..3
  const int lc  = l & 15;      // 0..15

  __shared__ _Float16 SB[16384];   // 32 KB: 2 bufs x (K 8KB | V 8KB)
  const char* sb = (const char*)SB;

  const int a0 = lc * 128 + (((0 + lg) ^ (lc & 7)) << 4);
  const int a1 = lc * 128 + (((4 + lg) ^ (lc & 7)) << 4);

  // Q fragments (B operand), 2 per wave: col=q=16*qa+lc, k=ks*32+8*lg+e
  f16x8 qf[2][2];
  {
    const float qs = 0.125f * 1.4426950408889634f;
    #pragma unroll
    for (int qa = 0; qa < 2; ++qa) {
      const float* qr = Q + ((size_t)bh * Sc + q0 + w * 32 + qa * 16 + lc) * Dc + 8 * lg;
      #pragma unroll
      for (int ks = 0; ks < 2; ++ks) {
        f16x8 t;
        #pragma unroll
        for (int e = 0; e < 8; ++e) t[e] = (_Float16)(qr[ks * 32 + e] * qs);
        qf[qa][ks] = t;
      }
    }
  }

  f32x4 o_acc[2][4];
  #pragma unroll
  for (int qa = 0; qa < 2; ++qa)
    #pragma unroll
    for (int nt = 0; nt < 4; ++nt) o_acc[qa][nt] = (f32x4){0.f, 0.f, 0.f, 0.f};
  float l_acc0 = 0.f, l_acc1 = 0.f;
  const float NEGL = -1.4426950e9f;   // exp2 -> exact 0 for masked keys

  const char* KswT = (const char*)(Ksw + (size_t)bh * Sc * Dc);
  const char* VswT = (const char*)(Vsw + (size_t)bh * Sc * Dc);
  const int row0 = q0 + w * 32 + lc;
  const int row1 = row0 + 16;
  const u64* Mb0 = MB + ((size_t)(b * NQ + (row0 >> 6)) * NKV) * 64 + (row0 & 63);
  const u64* Mb1 = MB + ((size_t)(b * NQ + (row1 >> 6)) * NKV) * 64 + (row1 & 63);

  // stage: wave w copies 2 KB of the 16 KB tile into buffer `buf` (2 gload16)
  auto stage = [&](int kvt, int buf) {
    const char* g = (w < 4) ? KswT + (size_t)kvt * 8192 + w * 2048
                            : VswT + (size_t)kvt * 8192 + (w - 4) * 2048;
    char* lb = (char*)SB + buf * 16384 + ((w < 4) ? w * 2048 : 8192 + (w - 4) * 2048);
    gload16(g + l * 16, lb);
    gload16(g + 1024 + l * 16, lb + 1024);
  };

  auto body = [&](int buf, u64 m0, u64 m1) {
    const int base = buf * 16384;
    // S^T = K Q^T for both q-fragments; K read once per nt
    f32x4 p[2][4];
    __builtin_amdgcn_s_setprio(1);
    #pragma unroll
    for (int nt = 0; nt < 4; ++nt) {
      const f16x8 k0 = *(const f16x8*)(sb + base + nt * 2048 + a0);
      const f16x8 k1 = *(const f16x8*)(sb + base + nt * 2048 + a1);
      #pragma unroll
      for (int qa = 0; qa < 2; ++qa) {
        f32x4 acc = (f32x4){0.f, 0.f, 0.f, 0.f};
        acc = mfma16(k0, qf[qa][0], acc);
        acc = mfma16(k1, qf[qa][1], acc);
        p[qa][nt] = acc;
      }
    }
    __builtin_amdgcn_s_setprio(0);
    // constant-max softmax: pe = exp2(mask ? s : NEGL)
    #pragma unroll
    for (int qa = 0; qa < 2; ++qa) {
      const u64 mbits = qa ? m1 : m0;
      #pragma unroll
      for (int nt = 0; nt < 4; ++nt) {
        const unsigned b4 = ((unsigned)(mbits >> (nt * 16 + 4 * lg))) & 0xFu;
        #pragma unroll
        for (int r = 0; r < 4; ++r)
          p[qa][nt][r] = fast_exp2(((b4 >> r) & 1u) ? p[qa][nt][r] : NEGL);
      }
    }
    // pack into PV A-fragments (pi-matched V) + l via fdot2
    f16x8 pa0[2], pa1[2];
    #pragma unroll
    for (int qa = 0; qa < 2; ++qa) {
      u32x4 u0, u1;
      #pragma unroll
      for (int i = 0; i < 4; ++i) {
        u0[i] = pkrtz(p[qa][i >> 1][(i & 1) * 2], p[qa][i >> 1][(i & 1) * 2 + 1]);
        u1[i] = pkrtz(p[qa][2 + (i >> 1)][(i & 1) * 2], p[qa][2 + (i >> 1)][(i & 1) * 2 + 1]);
      }
      float la = qa ? l_acc1 : l_acc0;
      #pragma unroll
      for (int i = 0; i < 4; ++i) { la = dot2acc(u0[i], la); la = dot2acc(u1[i], la); }
      if (qa) l_acc1 = la; else l_acc0 = la;
      pa0[qa] = __builtin_bit_cast(f16x8, u0);
      pa1[qa] = __builtin_bit_cast(f16x8, u1);
    }
    // O += P V : V read once per nt, shared by both fragments
    __builtin_amdgcn_s_setprio(1);
    #pragma unroll
    for (int nt = 0; nt < 4; ++nt) {
      const f16x8 v0 = *(const f16x8*)(sb + base + 8192 + nt * 2048 + a0);
      const f16x8 v1 = *(const f16x8*)(sb + base + 8192 + nt * 2048 + a1);
      o_acc[0][nt] = mfma16(pa0[0], v0, o_acc[0][nt]);
      o_acc[0][nt] = mfma16(pa1[0], v1, o_acc[0][nt]);
      o_acc[1][nt] = mfma16(pa0[1], v0, o_acc[1][nt]);
      o_acc[1][nt] = mfma16(pa1[1], v1, o_acc[1][nt]);
    }
    __builtin_amdgcn_s_setprio(0);
  };

  // ---- counted-vmcnt 2-buffer pipeline (per-iteration vmem = 2 gload + 2 mask = 4) ----
  u64 mA0 = Mb0[0], mA1 = Mb1[0];
  stage(0, 0);
  asm volatile("s_waitcnt vmcnt(0)" ::: "memory");
  __builtin_amdgcn_sched_barrier(0);
  __builtin_amdgcn_s_barrier();

  u64 mB0, mB1;
  for (int t = 0; t < NKV; t += 2) {
    // --- prefetch tile t+1 into B1, then run body(t) on B0 ---
    stage(t + 1, 1);
    mB0 = Mb0[(size_t)(t + 1) * 64];
    mB1 = Mb1[(size_t)(t + 1) * 64];
    asm volatile("s_waitcnt vmcnt(4)" ::: "memory");  // all but stage(t+1)+masks done
    __builtin_amdgcn_sched_barrier(0);
    __builtin_amdgcn_s_barrier();                      // B0 ready for all waves
    body(0, mA0, mA1);
    __builtin_amdgcn_s_barrier();                      // B0 readers done (WAR for stage(t+2))

    // --- prefetch tile t+2 into B0, then run body(t+1) on B1 ---
    if (t + 2 < NKV) {
      stage(t + 2, 0);
      mA0 = Mb0[(size_t)(t + 2) * 64];
      mA1 = Mb1[(size_t)(t + 2) * 64];
      asm volatile("s_waitcnt vmcnt(4)" ::: "memory");
    } else {
      asm volatile("s_waitcnt vmcnt(0)" ::: "memory");
    }
    __builtin_amdgcn_sched_barrier(0);
    __builtin_amdgcn_s_barrier();                      // B1 ready
    body(1, mB0, mB1);
    __builtin_amdgcn_s_barrier();                      // B1 readers done
  }

  // ---- epilogue: reduce l (additive), O /= l ----
  l_acc0 += __shfl_xor(l_acc0, 16, 64);
  l_acc0 += __shfl_xor(l_acc0, 32, 64);
  l_acc1 += __shfl_xor(l_acc1, 16, 64);
  l_acc1 += __shfl_xor(l_acc1, 32, 64);
  #pragma unroll
  for (int qa = 0; qa < 2; ++qa) {
    #pragma unroll
    for (int r = 0; r < 4; ++r) {
      const float li = 1.0f / __shfl(qa ? l_acc1 : l_acc0, 4 * lg + r, 64);
      float* orow = O + ((size_t)bh * Sc + q0 + w * 32 + qa * 16 + 4 * lg + r) * Dc + lc;
      #pragma unroll
      for (int nt = 0; nt < 4; ++nt)
        orow[nt * 16] = o_acc[qa][nt][r] * li;
    }
  }
}

// ---------------- Fallback (round-1 kernel, used if ws too small) ----------------
constexpr int LDSW = KVBLK + 8;

__global__ __launch_bounds__(256)
void attn_fwd_v1(const float* __restrict__ Q, const float* __restrict__ K,
                 const float* __restrict__ V, const int* __restrict__ M,
                 float* __restrict__ O)
{
  const int bid   = blockIdx.x;
  const int qtile = bid & 31;
  const int bh    = bid >> 5;
  const int b     = bh >> 4;

  const float* Qp = Q + ((size_t)bh * Sc + (size_t)qtile * 64) * Dc;
  const float* Kp = K + (size_t)bh * Sc * Dc;
  const float* Vp = V + (size_t)bh * Sc * Dc;
  const int*   Mp = M + (size_t)b * Sc * Sc + (size_t)qtile * 64 * Sc;
  float*       Op = O + ((size_t)bh * Sc + (size_t)qtile * 64) * Dc;

  __shared__ _Float16 Klds [KVBLK][LDSW];
  __shared__ _Float16 Vtlds[Dc]   [LDSW];
  __shared__ _Float16 Pl   [64]   [LDSW];

  const int tid = threadIdx.x;
  const int w   = tid >> 6;
  const int l   = tid & 63;
  const int lg  = l >> 4;
  const int lc  = l & 15;

  f16x8 qf[2];
  {
    const float qs = 0.125f * 1.4426950408889634f;
    const float* qrow = Qp + (size_t)(w * 16 + lc) * Dc + 8 * lg;
    #pragma unroll
    for (int ks = 0; ks < 2; ++ks) {
      f16x8 t;
      #pragma unroll
      for (int e = 0; e < 8; ++e) t[e] = (_Float16)(qrow[ks * 32 + e] * qs);
      qf[ks] = t;
    }
  }

  f32x4 o_acc[4];
  #pragma unroll
  for (int nt = 0; nt < 4; ++nt) o_acc[nt] = (f32x4){0.f, 0.f, 0.f, 0.f};
  float m_r[4], l_r[4];
  #pragma unroll
  for (int r = 0; r < 4; ++r) { m_r[r] = -3.0e38f; l_r[r] = 0.f; }
  const float NEGL = -1.4426950e9f;

  for (int kv = 0; kv < NKV; ++kv) {
    const float* Kt = Kp + (size_t)kv * KVBLK * Dc;
    const float* Vt = Vp + (size_t)kv * KVBLK * Dc;
    __syncthreads();
    {
      const int r = tid >> 2, c0 = (tid & 3) * 16;
      const float* src = Kt + (size_t)r * Dc + c0;
      f16x8 h0, h1;
      #pragma unroll
      for (int e = 0; e < 8; ++e) h0[e] = (_Float16)src[e];
      #pragma unroll
      for (int e = 0; e < 8; ++e) h1[e] = (_Float16)src[8 + e];
      *(f16x8*)&Klds[r][c0]     = h0;
      *(f16x8*)&Klds[r][c0 + 8] = h1;
    }
    {
      const int r0 = (tid >> 4) * 4, c0 = (tid & 15) * 4;
      float a_[4][4];
      #pragma unroll
      for (int i = 0; i < 4; ++i) {
        const float4 v4 = *(const float4*)(Vt + (size_t)(r0 + i) * Dc + c0);
        a_[i][0] = v4.x; a_[i][1] = v4.y; a_[i][2] = v4.z; a_[i][3] = v4.w;
      }
      #pragma unroll
      for (int j = 0; j < 4; ++j) {
        f16x4 t = {(_Float16)a_[0][j], (_Float16)a_[1][j],
                   (_Float16)a_[2][j], (_Float16)a_[3][j]};
        *(f16x4*)&Vtlds[c0 + j][r0] = t;
      }
    }
    __syncthreads();

    f32x4 s_acc[4];
    #pragma unroll
    for (int nt = 0; nt < 4; ++nt) {
      f32x4 acc = (f32x4){0.f, 0.f, 0.f, 0.f};
      #pragma unroll
      for (int ks = 0; ks < 2; ++ks) {
        f16x8 kf = *(const f16x8*)&Klds[nt * 16 + lc][ks * 32 + 8 * lg];
        acc = __builtin_amdgcn_mfma_f32_16x16x32_f16(qf[ks], kf, acc, 0, 0, 0);
      }
      s_acc[nt] = acc;
    }

    const int* mbase = Mp + (size_t)kv * KVBLK + lc;
    #pragma unroll
    for (int r = 0; r < 4; ++r) {
      const int qrow = w * 16 + 4 * lg + r;
      const int* mr = mbase + (size_t)qrow * Sc;
      float s0 = (mr[0]  != 0) ? s_acc[0][r] : NEGL;
      float s1 = (mr[16] != 0) ? s_acc[1][r] : NEGL;
      float s2 = (mr[32] != 0) ? s_acc[2][r] : NEGL;
      float s3 = (mr[48] != 0) ? s_acc[3][r] : NEGL;
      float mx = fmaxf(fmaxf(s0, s1), fmaxf(s2, s3));
      #pragma unroll
      for (int off = 1; off < 16; off <<= 1)
        mx = fmaxf(mx, __shfl_xor(mx, off, 64));
      const float mn   = fmaxf(m_r[r], mx);
      const float corr = fast_exp2(m_r[r] - mn);
      m_r[r] = mn;
      float p0 = fast_exp2(s0 - mn);
      float p1 = fast_exp2(s1 - mn);
      float p2 = fast_exp2(s2 - mn);
      float p3 = fast_exp2(s3 - mn);
      float rs = (p0 + p1) + (p2 + p3);
      #pragma unroll
      for (int off = 1; off < 16; off <<= 1)
        rs += __shfl_xor(rs, off, 64);
      l_r[r] = l_r[r] * corr + rs;
      #pragma unroll
      for (int nt = 0; nt < 4; ++nt) o_acc[nt][r] *= corr;
      Pl[qrow][lc]      = (_Float16)p0;
      Pl[qrow][16 + lc] = (_Float16)p1;
      Pl[qrow][32 + lc] = (_Float16)p2;
      Pl[qrow][48 + lc] = (_Float16)p3;
    }

    #pragma unroll
    for (int nt = 0; nt < 4; ++nt) {
      #pragma unroll
      for (int ks = 0; ks < 2; ++ks) {
        f16x8 pf = *(const f16x8*)&Pl[w * 16 + lc][ks * 32 + 8 * lg];
        f16x8 vf = *(const f16x8*)&Vtlds[nt * 16 + lc][ks * 32 + 8 * lg];
        o_acc[nt] = __builtin_amdgcn_mfma_f32_16x16x32_f16(pf, vf, o_acc[nt], 0, 0, 0);
      }
    }
  }

  #pragma unroll
  for (int r = 0; r < 4; ++r) {
    const float inv = 1.0f / l_r[r];
    float* orow = Op + (size_t)(w * 16 + 4 * lg + r) * Dc;
    #pragma unroll
    for (int nt = 0; nt < 4; ++nt)
      orow[nt * 16 + lc] = o_acc[nt][r] * inv;
  }
}

extern "C" void kernel_launch(void* const* d_in, const int* in_sizes, int n_in,
                              void* d_out, int out_size, void* d_ws, size_t ws_size,
                              hipStream_t stream) {
  (void)in_sizes; (void)n_in; (void)out_size;
  const float* Q = (const float*)d_in[0];
  const float* K = (const float*)d_in[1];
  const float* V = (const float*)d_in[2];
  const int*   M = (const int*)d_in[3];
  float*       O = (float*)d_out;

  const size_t nKV      = (size_t)Bc * Hc * Sc * Dc;        // 8,388,608
  const size_t bytesK16 = nKV * 2;                           // 16 MiB
  const size_t bytesMB  = (size_t)Bc * NQ * NKV * 64 * 8;    // 2 MiB
  const size_t need     = 2 * bytesK16 + bytesMB;

  if (ws_size >= need) {
    _Float16* K16  = (_Float16*)d_ws;
    _Float16* Vt16 = (_Float16*)((char*)d_ws + bytesK16);
    u64*      MBp  = (u64*)((char*)d_ws + 2 * bytesK16);
    hipLaunchKernelGGL(cvt_k_sw,   dim3(2048),  dim3(256), 0, stream, K, K16);
    hipLaunchKernelGGL(cvt_v_sw,   dim3(2048),  dim3(256), 0, stream, V, Vt16);
    hipLaunchKernelGGL(pack_mask,  dim3(65536), dim3(256), 0, stream, M, MBp);
    hipLaunchKernelGGL(attn_fwd11, dim3(512),   dim3(512), 0, stream, Q, K16, Vt16, MBp, O);
  } else {
    hipLaunchKernelGGL(attn_fwd_v1, dim3(2048), dim3(256), 0, stream, Q, K, V, M, O);
  }
}